// Round 5
// baseline (220.470 us; speedup 1.0000x reference)
//
#include <hip/hip_runtime.h>

// SparseMCFModel: the GNN is dead code. fw_e = 1/(outdeg(src_e)+1e-9) exactly
// (softmax over per-segment-constant scores). Flow loop collapses to node
// space: r_0 = invdeg; r_{k+1}[n] = relu(sum_{e:dst=n} r_k[src_e] - d0[n]) *
// invdeg[n]; flow[e] = r_10[src[e]]; cost = sum flow^2.
//
// R1->R2: no single-address cost atomic; CSR gather spmv.       1268 -> 428 us
// R2->R3: bucket partition (atomic-free except outdeg hist).     428 -> 284 us
// R3->R4: zero global atomics (src-partition outdeg), CHUNK 4096. 284 -> 219 us
// R4->R5: spmv train was ~100+ us of LDS float atomics. Finish the counting
//   sort: per-bucket fine_sort (LDS 128-ctr hist + scan + rank-scatter) gives
//   full CSR-by-dst; inner loop becomes atomic-free lane-pair-per-node gather
//   (2N threads, 2-way unrolled accumulators, shfl_xor combine). CHUNK
//   2048 (782 partition blocks) for build parallelism.

static constexpr int BLK      = 256;
static constexpr int SCAN_BLK = 1024;
static constexpr int CHUNK    = 2048;   // edges per partition block
static constexpr int LB       = 7;      // log2(nodes per bucket)
static constexpr int BN       = 128;    // nodes per bucket

// Pass 1: per-block LDS histograms over dst-buckets AND src-buckets.
__global__ void hist_kernel(const int* __restrict__ src, const int* __restrict__ dst,
                            int* __restrict__ counts, int E, int B, int nb, int M) {
    extern __shared__ int lh[];          // [0,B): dst bins, [B,2B): src bins
    int* lhd = lh;
    int* lhs = lh + B;
    for (int i = threadIdx.x; i < 2 * B; i += blockDim.x) lh[i] = 0;
    __syncthreads();
    int base = blockIdx.x * CHUNK;
    int end  = base + CHUNK < E ? base + CHUNK : E;
    for (int e = base + threadIdx.x; e < end; e += blockDim.x) {
        atomicAdd(&lhd[dst[e] >> LB], 1);   // LDS only — no write-through
        atomicAdd(&lhs[src[e] >> LB], 1);
    }
    __syncthreads();
    for (int i = threadIdx.x; i < B; i += blockDim.x) {
        counts[i * nb + blockIdx.x]     = lhd[i];   // bin-major
        counts[M + i * nb + blockIdx.x] = lhs[i];
    }
}

// exclusive scan of counts[M2] in place (3 kernels)
__global__ void scan_block_kernel(int* __restrict__ data, int* __restrict__ blocksum, int M2) {
    __shared__ int lds[SCAN_BLK];
    int t = threadIdx.x;
    int i = blockIdx.x * SCAN_BLK + t;
    int v = (i < M2) ? data[i] : 0;
    lds[t] = v;
    __syncthreads();
    for (int off = 1; off < SCAN_BLK; off <<= 1) {
        int tmp = (t >= off) ? lds[t - off] : 0;
        __syncthreads();
        lds[t] += tmp;
        __syncthreads();
    }
    if (i < M2) data[i] = lds[t] - v;
    if (t == SCAN_BLK - 1) blocksum[blockIdx.x] = lds[t];
}

// single-block parallel scan of blocksum -> blockoff (exclusive)
__global__ void scan_partials_kernel(const int* __restrict__ bsum, int* __restrict__ boff, int n) {
    __shared__ int lds[SCAN_BLK];
    __shared__ int carry_s;
    if (threadIdx.x == 0) carry_s = 0;
    __syncthreads();
    for (int base = 0; base < n; base += SCAN_BLK) {
        int i = base + threadIdx.x;
        int v = (i < n) ? bsum[i] : 0;
        lds[threadIdx.x] = v;
        __syncthreads();
        for (int off = 1; off < SCAN_BLK; off <<= 1) {
            int tmp = (threadIdx.x >= off) ? lds[threadIdx.x - off] : 0;
            __syncthreads();
            lds[threadIdx.x] += tmp;
            __syncthreads();
        }
        int incl = lds[threadIdx.x];
        int c = carry_s;
        if (i < n) boff[i] = c + incl - v;
        __syncthreads();
        if (threadIdx.x == SCAN_BLK - 1) carry_s = c + incl;
        __syncthreads();
    }
}

__global__ void scan_add_kernel(int* __restrict__ data, const int* __restrict__ boff, int M2) {
    int i = blockIdx.x * blockDim.x + threadIdx.x;
    if (i < M2) data[i] += boff[i >> 10];
}

// Pass 2a: byte-scatter src&127 grouped by src-bucket (for atomic-free outdeg).
__global__ void scatter_src_kernel(const int* __restrict__ src, const int* __restrict__ coff,
                                   unsigned char* __restrict__ psrc, int E, int B, int nb, int M) {
    extern __shared__ int loff[];
    for (int i = threadIdx.x; i < B; i += blockDim.x)
        loff[i] = coff[M + i * nb + blockIdx.x] - E;   // src half starts at E
    __syncthreads();
    int base = blockIdx.x * CHUNK;
    int end  = base + CHUNK < E ? base + CHUNK : E;
    for (int e = base + threadIdx.x; e < end; e += blockDim.x) {
        int s = src[e];
        int pos = atomicAdd(&loff[s >> LB], 1);        // LDS cursor
        psrc[pos] = (unsigned char)(s & (BN - 1));
    }
}

// Pass 2b: per src-bucket fine count -> invdeg, r0.
__global__ void count_src_kernel(const unsigned char* __restrict__ psrc, const int* __restrict__ coff,
                                 float* __restrict__ invdeg, float* __restrict__ r0,
                                 int N, int E, int B, int nb, int M) {
    __shared__ int cnt[BN];
    if (threadIdx.x < BN) cnt[threadIdx.x] = 0;
    __syncthreads();
    int b = blockIdx.x;
    int beg = coff[M + b * nb] - E;
    int end = (b + 1 < B) ? coff[M + (b + 1) * nb] - E : E;
    for (int e = beg + threadIdx.x; e < end; e += blockDim.x)
        atomicAdd(&cnt[psrc[e]], 1);
    __syncthreads();
    int g = (b << LB) + threadIdx.x;
    if (threadIdx.x < BN && g < N) {
        float v = 1.0f / ((float)cnt[threadIdx.x] + 1e-9f);
        invdeg[g] = v;
        r0[g] = v;   // r_0 = 1 * invdeg
    }
}

// Pass 3: scatter packed edges (src | ldst<<17) grouped by dst-bucket; fw fused.
__global__ void scatter_dst_kernel(const int* __restrict__ src, const int* __restrict__ dst,
                                   const float* __restrict__ invdeg, const int* __restrict__ coff,
                                   unsigned* __restrict__ packed, float* __restrict__ fw,
                                   int E, int B, int nb) {
    extern __shared__ int loff[];
    for (int i = threadIdx.x; i < B; i += blockDim.x)
        loff[i] = coff[i * nb + blockIdx.x];
    __syncthreads();
    int base = blockIdx.x * CHUNK;
    int end  = base + CHUNK < E ? base + CHUNK : E;
    for (int e = base + threadIdx.x; e < end; e += blockDim.x) {
        int s = src[e], d = dst[e];
        int pos = atomicAdd(&loff[d >> LB], 1);
        packed[pos] = (unsigned)s | ((unsigned)(d & (BN - 1)) << 17);
        fw[e] = invdeg[s];
    }
}

// Pass 4: per dst-bucket counting sort -> csr_src (sorted by dst), row_ptr.
__global__ void fine_sort_kernel(const unsigned* __restrict__ packed, const int* __restrict__ coff,
                                 int* __restrict__ csr_src, int* __restrict__ row_ptr,
                                 int N, int E, int B, int nb) {
    __shared__ int cnt[BN];
    __shared__ int off[BN];
    int t = threadIdx.x;
    int b = blockIdx.x;
    if (t < BN) cnt[t] = 0;
    __syncthreads();
    int beg = coff[b * nb];
    int end = (b + 1 < B) ? coff[(b + 1) * nb] : E;
    for (int e = beg + t; e < end; e += blockDim.x)
        atomicAdd(&cnt[packed[e] >> 17], 1);
    __syncthreads();
    if (t < BN) off[t] = cnt[t];
    __syncthreads();
    for (int s = 1; s < BN; s <<= 1) {          // Hillis-Steele inclusive
        int v = (t < BN && t >= s) ? off[t - s] : 0;
        __syncthreads();
        if (t < BN) off[t] += v;
        __syncthreads();
    }
    if (t < BN) {
        off[t] = beg + off[t] - cnt[t];          // exclusive + bucket base
        int g = (b << LB) + t;
        if (g < N) row_ptr[g] = off[t];
    }
    __syncthreads();
    for (int e = beg + t; e < end; e += blockDim.x) {
        unsigned v = packed[e];
        int pos = atomicAdd(&off[v >> 17], 1);   // LDS cursor
        csr_src[pos] = (int)(v & 0x1FFFFu);
    }
    if (b == 0 && t == 0) row_ptr[N] = E;
}

// Inner loop: lane-pair per node, atomic-free. Each lane sums half the row
// with 2 independent accumulators; shfl_xor(1) combines.
__global__ void spmv_csr2_kernel(const int* __restrict__ row_ptr, const int* __restrict__ csr_src,
                                 const float* __restrict__ r_in, const float* __restrict__ d0,
                                 const float* __restrict__ invdeg, float* __restrict__ r_out, int N) {
    int tid = blockIdx.x * blockDim.x + threadIdx.x;
    int n = tid >> 1;
    if (n >= N) return;
    int half = tid & 1;
    int beg = row_ptr[n], end = row_ptr[n + 1];
    int mid = beg + ((end - beg + 1) >> 1);
    int lo = half ? mid : beg;
    int hi = half ? end : mid;
    float a0 = 0.0f, a1 = 0.0f;
    int j = lo;
    for (; j + 1 < hi; j += 2) {
        a0 += r_in[csr_src[j]];
        a1 += r_in[csr_src[j + 1]];
    }
    if (j < hi) a0 += r_in[csr_src[j]];
    float a = a0 + a1;
    a += __shfl_xor(a, 1, 64);
    if (half == 0) {
        float p = a - d0[n];
        p = p > 0.0f ? p : 0.0f;
        r_out[n] = p * invdeg[n];
    }
}

// flow[e] = r10[src[e]]; partial sums of flow^2. int4 loads; scalar stores
// (flow = out+1 is only 4B-aligned).
__global__ void final_kernel(const int* __restrict__ src, const float* __restrict__ r_fin,
                             float* __restrict__ flow, float* __restrict__ partials, int E) {
    int i = blockIdx.x * blockDim.x + threadIdx.x;
    int E4 = E >> 2;
    float f2 = 0.0f;
    if (i < E4) {
        int4 s4 = ((const int4*)src)[i];
        float a = r_fin[s4.x], b = r_fin[s4.y], c = r_fin[s4.z], d = r_fin[s4.w];
        int e = i << 2;
        flow[e] = a; flow[e + 1] = b; flow[e + 2] = c; flow[e + 3] = d;
        f2 = a * a + b * b + c * c + d * d;
    }
    if (blockIdx.x == 0 && threadIdx.x == 0) {   // tail (E % 4)
        for (int e = E4 << 2; e < E; ++e) {
            float f = r_fin[src[e]];
            flow[e] = f;
            f2 += f * f;
        }
    }
    #pragma unroll
    for (int off = 32; off > 0; off >>= 1) f2 += __shfl_down(f2, off, 64);
    __shared__ float wsum[BLK / 64];
    int lane = threadIdx.x & 63, w = threadIdx.x >> 6;
    if (lane == 0) wsum[w] = f2;
    __syncthreads();
    if (threadIdx.x == 0) {
        float s = 0.0f;
        #pragma unroll
        for (int k = 0; k < BLK / 64; ++k) s += wsum[k];
        partials[blockIdx.x] = s;
    }
}

__global__ void reduce_cost_kernel(const float* __restrict__ partials, float* __restrict__ cost, int n) {
    float s = 0.0f;
    for (int i = threadIdx.x; i < n; i += blockDim.x) s += partials[i];
    #pragma unroll
    for (int off = 32; off > 0; off >>= 1) s += __shfl_down(s, off, 64);
    __shared__ float wsum[16];
    int lane = threadIdx.x & 63, w = threadIdx.x >> 6;
    if (lane == 0) wsum[w] = s;
    __syncthreads();
    if (threadIdx.x == 0) {
        float t = 0.0f;
        for (int k = 0; k < (int)(blockDim.x / 64); ++k) t += wsum[k];
        cost[0] = t;
    }
}

extern "C" void kernel_launch(void* const* d_in, const int* in_sizes, int n_in,
                              void* d_out, int out_size, void* d_ws, size_t ws_size,
                              hipStream_t stream) {
    const float* demands  = (const float*)d_in[0];
    const int*   edge_src = (const int*)d_in[2];
    const int*   edge_dst = (const int*)d_in[3];
    const int N = in_sizes[0];
    const int E = in_sizes[2];

    float* out  = (float*)d_out;
    float* cost = out;
    float* flow = out + 1;
    float* fw   = out + 1 + E;

    const int B   = (N + BN - 1) >> LB;              // buckets
    const int nb  = (E + CHUNK - 1) / CHUNK;         // partition blocks
    const int M   = B * nb;                          // per-key counts matrix
    const int M2  = 2 * M;                           // dst + src concatenated
    const int nbs = (M2 + SCAN_BLK - 1) / SCAN_BLK;  // scan blocks
    const int gridF = ((E >> 2) + BLK - 1) / BLK;    // final (vec4)
    const int gridS = (2 * N + BLK - 1) / BLK;       // spmv (lane-pair/node)

    auto align16 = [](size_t x) { return (x + 15) & ~size_t(15); };
    char* ws = (char*)d_ws;
    size_t o = 0;
    float*    invdeg   = (float*)(ws + o);    o += align16((size_t)N * 4);
    float*    r0       = (float*)(ws + o);    o += align16((size_t)N * 4);
    float*    r1       = (float*)(ws + o);    o += align16((size_t)N * 4);
    int*      row_ptr  = (int*)(ws + o);      o += align16((size_t)(N + 1) * 4);
    int*      counts   = (int*)(ws + o);      o += align16((size_t)M2 * 4);
    int*      blocksum = (int*)(ws + o);      o += align16((size_t)nbs * 4);
    int*      blockoff = (int*)(ws + o);      o += align16((size_t)nbs * 4);
    unsigned* packed   = (unsigned*)(ws + o); o += align16((size_t)E * 4);
    int*      csr_src  = (int*)(ws + o);      o += align16((size_t)E * 4);
    float*    partials = (float*)(ws + o);    o += align16((size_t)gridF * 4);
    // psrc aliases packed: written/read before packed is produced, dead after.
    unsigned char* psrc = (unsigned char*)packed;

    hist_kernel<<<nb, BLK, (size_t)(2 * B) * 4, stream>>>(edge_src, edge_dst, counts, E, B, nb, M);

    scan_block_kernel<<<nbs, SCAN_BLK, 0, stream>>>(counts, blocksum, M2);
    scan_partials_kernel<<<1, SCAN_BLK, 0, stream>>>(blocksum, blockoff, nbs);
    scan_add_kernel<<<(M2 + BLK - 1) / BLK, BLK, 0, stream>>>(counts, blockoff, M2);

    scatter_src_kernel<<<nb, BLK, (size_t)B * 4, stream>>>(edge_src, counts, psrc, E, B, nb, M);
    count_src_kernel<<<B, BLK, 0, stream>>>(psrc, counts, invdeg, r0, N, E, B, nb, M);

    scatter_dst_kernel<<<nb, BLK, (size_t)B * 4, stream>>>(edge_src, edge_dst, invdeg, counts,
                                                           packed, fw, E, B, nb);
    fine_sort_kernel<<<B, BLK, 0, stream>>>(packed, counts, csr_src, row_ptr, N, E, B, nb);

    float* r_cur = r0;
    float* r_nxt = r1;
    for (int it = 0; it < 10; ++it) {
        spmv_csr2_kernel<<<gridS, BLK, 0, stream>>>(row_ptr, csr_src, r_cur, demands, invdeg, r_nxt, N);
        float* t = r_cur; r_cur = r_nxt; r_nxt = t;
    }

    final_kernel<<<gridF, BLK, 0, stream>>>(edge_src, r_cur, flow, partials, E);
    reduce_cost_kernel<<<1, 1024, 0, stream>>>(partials, cost, gridF);
}

// Round 6
// 188.196 us; speedup vs baseline: 1.1715x; 1.1715x over previous
//
#include <hip/hip_runtime.h>

// SparseMCFModel: the GNN is dead code. fw_e = 1/(outdeg(src_e)+1e-9) exactly
// (softmax over per-segment-constant scores). Flow loop collapses to node
// space: r_0 = invdeg; r_{k+1}[n] = relu(sum_{e:dst=n} r_k[src_e] - d0[n]) *
// invdeg[n]; flow[e] = r_10[src[e]]; cost = sum flow^2.
//
// R1->R2: no single-address cost atomic; CSR gather spmv.       1268 -> 428 us
// R2->R3: bucket partition (atomic-free except outdeg hist).     428 -> 284 us
// R3->R4: zero global atomics, CHUNK 4096.                       284 -> 219 us
// R4->R5: full counting sort -> CSR-by-dst, atomic-free spmv.    219 -> 220 us
// R5->R6: build bookkeeping was the regression: M2=1.22M counts entries
//   touched 5x uncoalesced. LB 7->9 (B=196, BN=512) + CHUNK 4096 => M2=153K
//   (8x less). Fused src+dst scatter (one fewer 12.8MB pass). scan_add
//   dropped (boff applied inline). Per-wave replicated LDS counters (no
//   cross-wave atomic contention; fine_sort gets per-wave pre-reserved
//   cursors). fw pass gone: r carried as float2{r,invdeg}, final emits
//   flow+fw from one 8B gather. 19 -> 17 kernels.

static constexpr int BLK      = 256;
static constexpr int SCAN_BLK = 1024;
static constexpr int CHUNK    = 4096;   // edges per partition block
static constexpr int LB       = 9;      // log2(nodes per bucket)
static constexpr int BN       = 512;    // nodes per bucket

// Pass 1: per-block LDS histograms over dst-buckets AND src-buckets,
// 4x wave-replicated counters.
__global__ void hist_kernel(const int* __restrict__ src, const int* __restrict__ dst,
                            int* __restrict__ counts, int E, int B, int nb, int M) {
    extern __shared__ int lh[];              // 4 replicas x [0,B) dst | [B,2B) src
    const int nbins = 2 * B;
    for (int i = threadIdx.x; i < 4 * nbins; i += blockDim.x) lh[i] = 0;
    __syncthreads();
    int* my = lh + (threadIdx.x >> 6) * nbins;
    int base = blockIdx.x * CHUNK;
    int end  = base + CHUNK < E ? base + CHUNK : E;
    int i4beg = base >> 2, i4end = end >> 2;
    for (int i = i4beg + threadIdx.x; i < i4end; i += blockDim.x) {
        int4 s4 = ((const int4*)src)[i];
        int4 d4 = ((const int4*)dst)[i];
        atomicAdd(&my[d4.x >> LB], 1); atomicAdd(&my[B + (s4.x >> LB)], 1);
        atomicAdd(&my[d4.y >> LB], 1); atomicAdd(&my[B + (s4.y >> LB)], 1);
        atomicAdd(&my[d4.z >> LB], 1); atomicAdd(&my[B + (s4.z >> LB)], 1);
        atomicAdd(&my[d4.w >> LB], 1); atomicAdd(&my[B + (s4.w >> LB)], 1);
    }
    if (blockIdx.x == (int)gridDim.x - 1 && threadIdx.x == 0) {   // scalar tail
        for (int e = i4end << 2; e < end; ++e) {
            atomicAdd(&my[dst[e] >> LB], 1);
            atomicAdd(&my[B + (src[e] >> LB)], 1);
        }
    }
    __syncthreads();
    for (int i = threadIdx.x; i < nbins; i += blockDim.x) {
        int s = lh[i] + lh[nbins + i] + lh[2 * nbins + i] + lh[3 * nbins + i];
        if (i < B) counts[i * nb + blockIdx.x] = s;               // bin-major
        else       counts[M + (i - B) * nb + blockIdx.x] = s;
    }
}

// exclusive scan of counts[M2] in place; consumers apply boff themselves.
__global__ void scan_block_kernel(int* __restrict__ data, int* __restrict__ blocksum, int M2) {
    __shared__ int lds[SCAN_BLK];
    int t = threadIdx.x;
    int i = blockIdx.x * SCAN_BLK + t;
    int v = (i < M2) ? data[i] : 0;
    lds[t] = v;
    __syncthreads();
    for (int off = 1; off < SCAN_BLK; off <<= 1) {
        int tmp = (t >= off) ? lds[t - off] : 0;
        __syncthreads();
        lds[t] += tmp;
        __syncthreads();
    }
    if (i < M2) data[i] = lds[t] - v;
    if (t == SCAN_BLK - 1) blocksum[blockIdx.x] = lds[t];
}

__global__ void scan_partials_kernel(const int* __restrict__ bsum, int* __restrict__ boff, int n) {
    __shared__ int lds[SCAN_BLK];
    __shared__ int carry_s;
    if (threadIdx.x == 0) carry_s = 0;
    __syncthreads();
    for (int base = 0; base < n; base += SCAN_BLK) {
        int i = base + threadIdx.x;
        int v = (i < n) ? bsum[i] : 0;
        lds[threadIdx.x] = v;
        __syncthreads();
        for (int off = 1; off < SCAN_BLK; off <<= 1) {
            int tmp = (threadIdx.x >= off) ? lds[threadIdx.x - off] : 0;
            __syncthreads();
            lds[threadIdx.x] += tmp;
            __syncthreads();
        }
        int incl = lds[threadIdx.x];
        int c = carry_s;
        if (i < n) boff[i] = c + incl - v;
        __syncthreads();
        if (threadIdx.x == SCAN_BLK - 1) carry_s = c + incl;
        __syncthreads();
    }
}

// Pass 2: FUSED scatter: packed edges by dst-bucket + src bytes by src-bucket.
__global__ void fused_scatter_kernel(const int* __restrict__ src, const int* __restrict__ dst,
                                     const int* __restrict__ counts, const int* __restrict__ boff,
                                     unsigned* __restrict__ packed, unsigned short* __restrict__ psrc,
                                     int E, int B, int nb, int M) {
    extern __shared__ int loff[];            // [0,B): dst cursors, [B,2B): src cursors
    int b = blockIdx.x;
    for (int i = threadIdx.x; i < B; i += blockDim.x) {
        int id  = i * nb + b;
        int id2 = M + i * nb + b;
        loff[i]     = counts[id]  + boff[id >> 10];
        loff[B + i] = counts[id2] + boff[id2 >> 10] - E;   // src half starts at E
    }
    __syncthreads();
    int base = b * CHUNK;
    int end  = base + CHUNK < E ? base + CHUNK : E;
    int i4beg = base >> 2, i4end = end >> 2;
    for (int i = i4beg + threadIdx.x; i < i4end; i += blockDim.x) {
        int4 s4 = ((const int4*)src)[i];
        int4 d4 = ((const int4*)dst)[i];
        #pragma unroll
        for (int k = 0; k < 4; ++k) {
            int s = (k == 0) ? s4.x : (k == 1) ? s4.y : (k == 2) ? s4.z : s4.w;
            int d = (k == 0) ? d4.x : (k == 1) ? d4.y : (k == 2) ? d4.z : d4.w;
            int pos = atomicAdd(&loff[d >> LB], 1);
            packed[pos] = (unsigned)s | ((unsigned)(d & (BN - 1)) << 17);
            int pos2 = atomicAdd(&loff[B + (s >> LB)], 1);
            psrc[pos2] = (unsigned short)(s & (BN - 1));
        }
    }
    if (b == (int)gridDim.x - 1 && threadIdx.x == 0) {     // scalar tail
        for (int e = i4end << 2; e < end; ++e) {
            int s = src[e], d = dst[e];
            int pos = atomicAdd(&loff[d >> LB], 1);
            packed[pos] = (unsigned)s | ((unsigned)(d & (BN - 1)) << 17);
            int pos2 = atomicAdd(&loff[B + (s >> LB)], 1);
            psrc[pos2] = (unsigned short)(s & (BN - 1));
        }
    }
}

// Pass 3: per src-bucket fine count -> rz0 = {invdeg, invdeg}. 8x replicated ctrs.
__global__ void count_src_kernel(const unsigned short* __restrict__ psrc,
                                 const int* __restrict__ counts, const int* __restrict__ boff,
                                 float2* __restrict__ rz0, int N, int E, int B, int nb, int M) {
    __shared__ int cnt[8 * BN];
    int t = threadIdx.x;
    for (int i = t; i < 8 * BN; i += blockDim.x) cnt[i] = 0;
    __syncthreads();
    int b = blockIdx.x;
    int id  = M + b * nb;
    int beg = counts[id] + boff[id >> 10] - E;
    int end;
    if (b + 1 < B) { int id2 = M + (b + 1) * nb; end = counts[id2] + boff[id2 >> 10] - E; }
    else end = E;
    int w = t >> 6;
    for (int e = beg + t; e < end; e += blockDim.x)
        atomicAdd(&cnt[(w << 9) + psrc[e]], 1);
    __syncthreads();
    int g = (b << LB) + t;
    if (t < BN && g < N) {
        int tot = 0;
        #pragma unroll
        for (int r = 0; r < 8; ++r) tot += cnt[(r << 9) + t];
        float v = 1.0f / ((float)tot + 1e-9f);
        rz0[g] = make_float2(v, v);    // r_0 = invdeg; .y carries invdeg forever
    }
}

// Pass 4: per dst-bucket counting sort -> csr_src, row_ptr. Per-wave cursors.
__global__ void fine_sort_kernel(const unsigned* __restrict__ packed,
                                 const int* __restrict__ counts, const int* __restrict__ boff,
                                 int* __restrict__ csr_src, int* __restrict__ row_ptr,
                                 int N, int E, int B, int nb) {
    __shared__ int cnt[8 * BN];
    __shared__ int off[BN];
    int t = threadIdx.x;
    int b = blockIdx.x;
    for (int i = t; i < 8 * BN; i += blockDim.x) cnt[i] = 0;
    __syncthreads();
    int id  = b * nb;
    int beg = counts[id] + boff[id >> 10];
    int end;
    if (b + 1 < B) { int id2 = (b + 1) * nb; end = counts[id2] + boff[id2 >> 10]; }
    else end = E;
    int w = t >> 6;
    for (int e = beg + t; e < end; e += blockDim.x)
        atomicAdd(&cnt[(w << 9) + (packed[e] >> 17)], 1);
    __syncthreads();
    int tot = 0;
    {
        #pragma unroll
        for (int r = 0; r < 8; ++r) tot += cnt[(r << 9) + t];
        off[t] = tot;
    }
    __syncthreads();
    for (int s = 1; s < BN; s <<= 1) {            // Hillis-Steele inclusive
        int v = (t >= s) ? off[t - s] : 0;
        __syncthreads();
        off[t] += v;
        __syncthreads();
    }
    int excl = beg + off[t] - tot;
    {
        int g = (b << LB) + t;
        if (g < N) row_ptr[g] = excl;
        // per-wave pre-reserved cursor ranges: zero cross-wave contention
        int base2 = excl;
        #pragma unroll
        for (int r = 0; r < 8; ++r) {
            int c = cnt[(r << 9) + t];
            cnt[(r << 9) + t] = base2;
            base2 += c;
        }
    }
    __syncthreads();
    for (int e = beg + t; e < end; e += blockDim.x) {
        unsigned v = packed[e];
        int pos = atomicAdd(&cnt[(w << 9) + (v >> 17)], 1);
        csr_src[pos] = (int)(v & 0x1FFFFu);
    }
    if (b == 0 && t == 0) row_ptr[N] = E;
}

// Inner loop: lane-pair per node, atomic-free. rz = {r, invdeg}.
__global__ void spmv_csr2_kernel(const int* __restrict__ row_ptr, const int* __restrict__ csr_src,
                                 const float2* __restrict__ rz_in, const float* __restrict__ d0,
                                 float2* __restrict__ rz_out, int N) {
    int tid = blockIdx.x * blockDim.x + threadIdx.x;
    int n = tid >> 1;
    if (n >= N) return;
    int half = tid & 1;
    int beg = row_ptr[n], end = row_ptr[n + 1];
    int mid = beg + ((end - beg + 1) >> 1);
    int lo = half ? mid : beg;
    int hi = half ? end : mid;
    float a0 = 0.0f, a1 = 0.0f;
    int j = lo;
    for (; j + 1 < hi; j += 2) {
        a0 += rz_in[csr_src[j]].x;
        a1 += rz_in[csr_src[j + 1]].x;
    }
    if (j < hi) a0 += rz_in[csr_src[j]].x;
    float a = a0 + a1;
    a += __shfl_xor(a, 1, 64);
    if (half == 0) {
        float inv = rz_in[n].y;
        float p = a - d0[n];
        p = p > 0.0f ? p : 0.0f;
        rz_out[n] = make_float2(p * inv, inv);
    }
}

// flow[e] = rz.x, fw[e] = rz.y from ONE 8B gather; partial sums of flow^2.
__global__ void final_kernel(const int* __restrict__ src, const float2* __restrict__ rz,
                             float* __restrict__ flow, float* __restrict__ fw,
                             float* __restrict__ partials, int E) {
    int i = blockIdx.x * blockDim.x + threadIdx.x;
    int E4 = E >> 2;
    float f2 = 0.0f;
    if (i < E4) {
        int4 s4 = ((const int4*)src)[i];
        float2 a = rz[s4.x], b = rz[s4.y], c = rz[s4.z], d = rz[s4.w];
        int e = i << 2;
        flow[e] = a.x; flow[e + 1] = b.x; flow[e + 2] = c.x; flow[e + 3] = d.x;
        fw[e]   = a.y; fw[e + 1]   = b.y; fw[e + 2]   = c.y; fw[e + 3]   = d.y;
        f2 = a.x * a.x + b.x * b.x + c.x * c.x + d.x * d.x;
    }
    if (blockIdx.x == 0 && threadIdx.x == 0) {   // tail (E % 4)
        for (int e = E4 << 2; e < E; ++e) {
            float2 a = rz[src[e]];
            flow[e] = a.x; fw[e] = a.y;
            f2 += a.x * a.x;
        }
    }
    #pragma unroll
    for (int off = 32; off > 0; off >>= 1) f2 += __shfl_down(f2, off, 64);
    __shared__ float wsum[BLK / 64];
    int lane = threadIdx.x & 63, w = threadIdx.x >> 6;
    if (lane == 0) wsum[w] = f2;
    __syncthreads();
    if (threadIdx.x == 0) {
        float s = 0.0f;
        #pragma unroll
        for (int k = 0; k < BLK / 64; ++k) s += wsum[k];
        partials[blockIdx.x] = s;
    }
}

__global__ void reduce_cost_kernel(const float* __restrict__ partials, float* __restrict__ cost, int n) {
    float s = 0.0f;
    for (int i = threadIdx.x; i < n; i += blockDim.x) s += partials[i];
    #pragma unroll
    for (int off = 32; off > 0; off >>= 1) s += __shfl_down(s, off, 64);
    __shared__ float wsum[16];
    int lane = threadIdx.x & 63, w = threadIdx.x >> 6;
    if (lane == 0) wsum[w] = s;
    __syncthreads();
    if (threadIdx.x == 0) {
        float t = 0.0f;
        for (int k = 0; k < (int)(blockDim.x / 64); ++k) t += wsum[k];
        cost[0] = t;
    }
}

extern "C" void kernel_launch(void* const* d_in, const int* in_sizes, int n_in,
                              void* d_out, int out_size, void* d_ws, size_t ws_size,
                              hipStream_t stream) {
    const float* demands  = (const float*)d_in[0];
    const int*   edge_src = (const int*)d_in[2];
    const int*   edge_dst = (const int*)d_in[3];
    const int N = in_sizes[0];
    const int E = in_sizes[2];

    float* out  = (float*)d_out;
    float* cost = out;
    float* flow = out + 1;
    float* fw   = out + 1 + E;

    const int B   = (N + BN - 1) >> LB;              // 196 buckets
    const int nb  = (E + CHUNK - 1) / CHUNK;         // 391 partition blocks
    const int M   = B * nb;
    const int M2  = 2 * M;                           // 153K
    const int nbs = (M2 + SCAN_BLK - 1) / SCAN_BLK;
    const int gridF = ((E >> 2) + BLK - 1) / BLK;
    const int gridS = (2 * N + BLK - 1) / BLK;

    auto align16 = [](size_t x) { return (x + 15) & ~size_t(15); };
    char* ws = (char*)d_ws;
    size_t o = 0;
    float2*   rz0      = (float2*)(ws + o);   o += align16((size_t)N * 8);
    float2*   rz1      = (float2*)(ws + o);   o += align16((size_t)N * 8);
    int*      row_ptr  = (int*)(ws + o);      o += align16((size_t)(N + 1) * 4);
    int*      counts   = (int*)(ws + o);      o += align16((size_t)M2 * 4);
    int*      blocksum = (int*)(ws + o);      o += align16((size_t)nbs * 4);
    int*      blockoff = (int*)(ws + o);      o += align16((size_t)nbs * 4);
    unsigned* packed   = (unsigned*)(ws + o); o += align16((size_t)E * 4);
    unsigned short* psrc = (unsigned short*)(ws + o); o += align16((size_t)E * 2);
    int*      csr_src  = (int*)(ws + o);      o += align16((size_t)E * 4);
    float*    partials = (float*)(ws + o);    o += align16((size_t)gridF * 4);

    hist_kernel<<<nb, BLK, (size_t)(8 * B) * 4, stream>>>(edge_src, edge_dst, counts, E, B, nb, M);
    scan_block_kernel<<<nbs, SCAN_BLK, 0, stream>>>(counts, blocksum, M2);
    scan_partials_kernel<<<1, SCAN_BLK, 0, stream>>>(blocksum, blockoff, nbs);

    fused_scatter_kernel<<<nb, BLK, (size_t)(2 * B) * 4, stream>>>(
        edge_src, edge_dst, counts, blockoff, packed, psrc, E, B, nb, M);
    count_src_kernel<<<B, BN, 0, stream>>>(psrc, counts, blockoff, rz0, N, E, B, nb, M);
    fine_sort_kernel<<<B, BN, 0, stream>>>(packed, counts, blockoff, csr_src, row_ptr, N, E, B, nb);

    float2* r_cur = rz0;
    float2* r_nxt = rz1;
    for (int it = 0; it < 10; ++it) {
        spmv_csr2_kernel<<<gridS, BLK, 0, stream>>>(row_ptr, csr_src, r_cur, demands, r_nxt, N);
        float2* t = r_cur; r_cur = r_nxt; r_nxt = t;
    }

    final_kernel<<<gridF, BLK, 0, stream>>>(edge_src, r_cur, flow, fw, partials, E);
    reduce_cost_kernel<<<1, 1024, 0, stream>>>(partials, cost, gridF);
}